// Round 1
// 679.836 us; speedup vs baseline: 1.0659x; 1.0659x over previous
//
#include <hip/hip_runtime.h>
#include <hip/hip_bf16.h>

// B=8, S=2048, H=1024 — split-bf16 (fp32-emulation) MFMA pipeline.
//   x  -> x_hi/x_lo bf16; W -> Wt_hi/lo (transposed)
//   xw     = x @ W        3-pass split-bf16 MFMA -> xw_hi/lo (dead ctx region of d_out)
//   scores = xw @ x^T     3-pass split-bf16 MFMA -> attn region (fp32)   [8-PHASE 256²]
//   attn   = softmax      in place + bf16 copy
//   ctx    = attn @ x     1-pass bf16 MFMA (NT via xT)
//
// Round 5: gemm_sc3 rewritten as 256²-tile 8-wave 4-phase-per-K-tile schedule
// (T3+T4+T5): raw s_barrier, counted s_waitcnt vmcnt(6/6/4) — never drained to 0
// in the main loop — setprio(1) around each 24-MFMA cluster, sched_barrier(0)
// pins. B fragments live in registers across each K-tile (reloaded post-MFMA in
// phases 2/3 of the previous tile). LDS 128 KB: 2 bufs x {AsH,AsL,BsH,BsL} x 16 KB,
// logical BK=32. Same zero-conflict chunk-XOR swizzle as round 4 (write: source
// chunk = (tid&3)^((row'>>1)&3); read: chunk = quad^((m16>>1)&3)). Accumulation
// order per element identical to round 4 -> bit-identical scores.

#define BB 8
#define SS 2048
#define HH 1024

typedef __attribute__((ext_vector_type(8))) short bf16x8;
typedef __attribute__((ext_vector_type(4))) float f32x4;

__device__ __forceinline__ void async_load16(const void* gsrc, void* ldst) {
    typedef const unsigned int __attribute__((address_space(1)))* gp_t;
    typedef unsigned int __attribute__((address_space(3)))* lp_t;
    __builtin_amdgcn_global_load_lds((gp_t)gsrc, (lp_t)ldst, 16, 0, 0);
}

__device__ __forceinline__ unsigned short f2b(float f) {
    __hip_bfloat16 h = __float2bfloat16(f);
    return *(unsigned short*)&h;
}
__device__ __forceinline__ float b2f(unsigned short u) {
    __hip_bfloat16 h = *(__hip_bfloat16*)&u;
    return __bfloat162float(h);
}

// ----------------------------------------------------------- split x -> hi/lo bf16
__global__ __launch_bounds__(256) void split_x(const float* __restrict__ X,
                                               unsigned short* __restrict__ Xh,
                                               unsigned short* __restrict__ Xl) {
    const size_t i = ((size_t)blockIdx.x * 256 + threadIdx.x) * 8;
    float4 a = *(const float4*)(X + i);
    float4 b = *(const float4*)(X + i + 4);
    ushort4 h0, h1, l0, l1;
    float v, hf;
    v = a.x; h0.x = f2b(v); hf = b2f(h0.x); l0.x = f2b(v - hf);
    v = a.y; h0.y = f2b(v); hf = b2f(h0.y); l0.y = f2b(v - hf);
    v = a.z; h0.z = f2b(v); hf = b2f(h0.z); l0.z = f2b(v - hf);
    v = a.w; h0.w = f2b(v); hf = b2f(h0.w); l0.w = f2b(v - hf);
    v = b.x; h1.x = f2b(v); hf = b2f(h1.x); l1.x = f2b(v - hf);
    v = b.y; h1.y = f2b(v); hf = b2f(h1.y); l1.y = f2b(v - hf);
    v = b.z; h1.z = f2b(v); hf = b2f(h1.z); l1.z = f2b(v - hf);
    v = b.w; h1.w = f2b(v); hf = b2f(h1.w); l1.w = f2b(v - hf);
    *(ushort4*)(Xh + i) = h0; *(ushort4*)(Xh + i + 4) = h1;
    *(ushort4*)(Xl + i) = l0; *(ushort4*)(Xl + i + 4) = l1;
}

// ------------------------------------- W [k][n] -> Wt hi/lo [n][k] (bf16 split, transpose)
__global__ __launch_bounds__(256) void split_wT(const float* __restrict__ W,
                                                unsigned short* __restrict__ Th,
                                                unsigned short* __restrict__ Tl) {
    const int k0 = blockIdx.y * 64, n0 = blockIdx.x * 64;
    __shared__ float tile[64][65];
#pragma unroll
    for (int q = 0; q < 16; q++) {
        int idx = q * 256 + threadIdx.x;
        int r = idx >> 6, c = idx & 63;
        tile[r][c] = W[(size_t)(k0 + r) * HH + n0 + c];
    }
    __syncthreads();
#pragma unroll
    for (int q = 0; q < 16; q++) {
        int idx = q * 256 + threadIdx.x;
        int r = idx >> 6, c = idx & 63;
        float v = tile[c][r];
        unsigned short h = f2b(v);
        Th[(size_t)(n0 + r) * HH + k0 + c] = h;
        Tl[(size_t)(n0 + r) * HH + k0 + c] = f2b(v - b2f(h));
    }
}

// ---------------- 3-pass split-bf16 MFMA GEMM (NT), 128x128 tile, BK=32, emits bf16 hi/lo
__global__ __launch_bounds__(256) void gemm_xw3(const unsigned short* __restrict__ Ah,
                                                const unsigned short* __restrict__ Al,
                                                const unsigned short* __restrict__ Bh,
                                                const unsigned short* __restrict__ Bl,
                                                unsigned short* __restrict__ Ch,
                                                unsigned short* __restrict__ Cl) {
    const int b = blockIdx.z;
    const int i0 = blockIdx.y * 128, n0 = blockIdx.x * 128;
    const unsigned short* A_h = Ah + (size_t)b * SS * HH;
    const unsigned short* A_l = Al + (size_t)b * SS * HH;

    __shared__ __align__(16) unsigned short AsH[128 * 32];
    __shared__ __align__(16) unsigned short AsL[128 * 32];
    __shared__ __align__(16) unsigned short BsH[128 * 32];
    __shared__ __align__(16) unsigned short BsL[128 * 32];

    const int tid = threadIdx.x;
    const int wave = tid >> 6, lane = tid & 63;
    const int m16 = lane & 15, quad = lane >> 4;
    const int wy = wave >> 1, wx = wave & 1;
    const int rowA = tid >> 2;
    const int kq = (tid & 3) ^ ((rowA >> 1) & 3);   // XOR-swizzled source chunk

    f32x4 acc[4][4] = {};

    for (int k0 = 0; k0 < HH; k0 += 32) {
        const size_t ga0 = (size_t)(i0 + rowA) * HH + k0 + kq * 8;
        const size_t ga1 = (size_t)(i0 + 64 + rowA) * HH + k0 + kq * 8;
        const size_t gb0 = (size_t)(n0 + rowA) * HH + k0 + kq * 8;
        const size_t gb1 = (size_t)(n0 + 64 + rowA) * HH + k0 + kq * 8;
        async_load16(A_h + ga0, (char*)AsH + wave * 1024);
        async_load16(A_h + ga1, (char*)AsH + 4096 + wave * 1024);
        async_load16(A_l + ga0, (char*)AsL + wave * 1024);
        async_load16(A_l + ga1, (char*)AsL + 4096 + wave * 1024);
        async_load16(Bh + gb0, (char*)BsH + wave * 1024);
        async_load16(Bh + gb1, (char*)BsH + 4096 + wave * 1024);
        async_load16(Bl + gb0, (char*)BsL + wave * 1024);
        async_load16(Bl + gb1, (char*)BsL + 4096 + wave * 1024);
        __syncthreads();

        const int cs = quad ^ ((m16 >> 1) & 3);     // swizzled read chunk
        const int offA = (wy * 64 + m16) * 32 + cs * 8;
        const int offB = (wx * 64 + m16) * 32 + cs * 8;
        bf16x8 ah[4], al[4], bh[4], bl[4];
#pragma unroll
        for (int r = 0; r < 4; r++) {
            ah[r] = *(const bf16x8*)(AsH + offA + r * 16 * 32);
            al[r] = *(const bf16x8*)(AsL + offA + r * 16 * 32);
        }
#pragma unroll
        for (int c = 0; c < 4; c++) {
            bh[c] = *(const bf16x8*)(BsH + offB + c * 16 * 32);
            bl[c] = *(const bf16x8*)(BsL + offB + c * 16 * 32);
        }
#pragma unroll
        for (int r = 0; r < 4; r++)
#pragma unroll
            for (int c = 0; c < 4; c++) {
                acc[r][c] = __builtin_amdgcn_mfma_f32_16x16x32_bf16(ah[r], bh[c], acc[r][c], 0, 0, 0);
                acc[r][c] = __builtin_amdgcn_mfma_f32_16x16x32_bf16(ah[r], bl[c], acc[r][c], 0, 0, 0);
                acc[r][c] = __builtin_amdgcn_mfma_f32_16x16x32_bf16(al[r], bh[c], acc[r][c], 0, 0, 0);
            }
        __syncthreads();
    }

    unsigned short* ChB = Ch + (size_t)b * SS * HH;
    unsigned short* ClB = Cl + (size_t)b * SS * HH;
#pragma unroll
    for (int r = 0; r < 4; r++) {
        const int row = i0 + wy * 64 + r * 16 + quad * 4;
#pragma unroll
        for (int c = 0; c < 4; c++) {
            const int col = n0 + wx * 64 + c * 16 + m16;
#pragma unroll
            for (int reg = 0; reg < 4; reg++) {
                float v = acc[r][c][reg];
                unsigned short h = f2b(v);
                ChB[(size_t)(row + reg) * HH + col] = h;
                ClB[(size_t)(row + reg) * HH + col] = f2b(v - b2f(h));
            }
        }
    }
}

// ---------------- scores = xw @ x^T (NT), 3-pass split-bf16 MFMA, fp32 out
// 256x256 tile, 8 waves (2M x 4N, wave tile 128x64), logical BK=32.
// 4 phases per K-tile: (mh,nh) quadrants, 24 MFMA each, 2 staging calls each.
// LDS double-buffered: buf x {AsH,AsL,BsH,BsL} x 16 KB = 128 KB.
//   A-mh call (8 KB, 128 rows): r' -> row mh*64 + (r'&63) + (r'>>6)*128
//   B-nh call (8 KB, 128 rows): r' -> row (r'>>5)*64 + nh*32 + (r'&31)
// Staging schedule at tile t: ph0/ph1 -> A-mh0/A-mh1 of t+1 (into buf t+1),
//                             ph2/ph3 -> B-nh0/B-nh1 of t+2 (into buf t).
// B regs for tile t+1 loaded post-MFMA at t-ph2/t-ph3 from buf t+1.
// Counted waits (steady state, 2 issues/phase): ph1 vmcnt(6), ph2 vmcnt(6)
// [completes B-nh0(t+1) before its post-MFMA ds_read], ph3 vmcnt(4)
// [completes B-nh1(t+1) and A-mh0(t+1)]. Queue never drained below 4.
__global__ __launch_bounds__(512, 2) void gemm_sc3_8p(const unsigned short* __restrict__ Ah,
                                                      const unsigned short* __restrict__ Al,
                                                      const unsigned short* __restrict__ Bh,
                                                      const unsigned short* __restrict__ Bl,
                                                      float* __restrict__ SC) {
    const int b = blockIdx.z;
    const int i0 = blockIdx.y * 256, j0 = blockIdx.x * 256;
    const unsigned short* A_h = Ah + (size_t)b * SS * HH;
    const unsigned short* A_l = Al + (size_t)b * SS * HH;
    const unsigned short* B_h = Bh + (size_t)b * SS * HH;
    const unsigned short* B_l = Bl + (size_t)b * SS * HH;

    __shared__ __align__(16) unsigned short lds[65536];   // 128 KB

    const int tid = threadIdx.x;
    const int wave = tid >> 6, lane = tid & 63;
    const int m16 = lane & 15, quad = lane >> 4;
    const int wy = wave >> 2, wx = wave & 3;             // 2M x 4N wave grid
    const int rP = tid >> 2;                              // within-call row index 0..127
    const int kq = (tid & 3) ^ ((rP >> 1) & 3);           // swizzled source chunk
    const int cs = quad ^ ((m16 >> 1) & 3);               // swizzled read chunk
    const int wt16 = wave * 1024;                         // byte offset of wave slice in a call
    const int rowA_off = (rP & 63) + ((rP >> 6) << 7);    // + mh*64 -> global A row
    const int rowB_off = ((rP >> 5) << 6) + (rP & 31);    // + nh*32 -> global B row

    const size_t aOff = (size_t)(i0 + rowA_off) * HH + kq * 8;
    const size_t bOff = (size_t)(j0 + rowB_off) * HH + kq * 8;

    f32x4 acc[2][4][2][2] = {};                           // [mh][mi][nh][nj]
    bf16x8 a_h[4], a_l[4], b_h[2][2], b_l[2][2];

    // LDS ushort-offsets: buf*32768 + mat*8192, mats: 0 AsH, 1 AsL, 2 BsH, 3 BsL.
#define STG_A(mh, kt, buf) do { \
        const size_t o_ = aOff + (size_t)(mh) * 64 * HH + (size_t)(kt) * 32; \
        async_load16(A_h + o_, (char*)lds + ((buf) * 32768 + (mh) * 4096) * 2 + wt16); \
        async_load16(A_l + o_, (char*)lds + ((buf) * 32768 + 8192 + (mh) * 4096) * 2 + wt16); \
    } while (0)
#define STG_B(nh, kt, buf) do { \
        const size_t o_ = bOff + (size_t)(nh) * 32 * HH + (size_t)(kt) * 32; \
        async_load16(B_h + o_, (char*)lds + ((buf) * 32768 + 16384 + (nh) * 4096) * 2 + wt16); \
        async_load16(B_l + o_, (char*)lds + ((buf) * 32768 + 24576 + (nh) * 4096) * 2 + wt16); \
    } while (0)
#define RD_A(mh, buf) do { \
        const int s0_ = (buf) * 32768 + ((mh) * 128 + wy * 64 + m16) * 32 + cs * 8; \
        _Pragma("unroll") for (int mi = 0; mi < 4; ++mi) { \
            a_h[mi] = *(const bf16x8*)&lds[s0_ + mi * 512]; \
            a_l[mi] = *(const bf16x8*)&lds[8192 + s0_ + mi * 512]; \
        } } while (0)
#define RD_B(nh, buf) do { \
        const int s0_ = (buf) * 32768 + ((nh) * 128 + wx * 32 + m16) * 32 + cs * 8; \
        _Pragma("unroll") for (int nj = 0; nj < 2; ++nj) { \
            b_h[nh][nj] = *(const bf16x8*)&lds[16384 + s0_ + nj * 512]; \
            b_l[nh][nj] = *(const bf16x8*)&lds[24576 + s0_ + nj * 512]; \
        } } while (0)
#define MFMA_PH(mh, nh) \
        __builtin_amdgcn_s_setprio(1); \
        _Pragma("unroll") for (int mi = 0; mi < 4; ++mi) \
        _Pragma("unroll") for (int nj = 0; nj < 2; ++nj) { \
            acc[mh][mi][nh][nj] = __builtin_amdgcn_mfma_f32_16x16x32_bf16(a_h[mi], b_h[nh][nj], acc[mh][mi][nh][nj], 0, 0, 0); \
            acc[mh][mi][nh][nj] = __builtin_amdgcn_mfma_f32_16x16x32_bf16(a_h[mi], b_l[nh][nj], acc[mh][mi][nh][nj], 0, 0, 0); \
            acc[mh][mi][nh][nj] = __builtin_amdgcn_mfma_f32_16x16x32_bf16(a_l[mi], b_h[nh][nj], acc[mh][mi][nh][nj], 0, 0, 0); \
        } \
        __builtin_amdgcn_s_setprio(0);

    // ---- prologue: A(0),B(0) -> buf0 (8 calls), B(1) -> buf1 (4 calls)
    STG_A(0, 0, 0); STG_A(1, 0, 0);
    STG_B(0, 0, 0); STG_B(1, 0, 0);
    STG_B(0, 1, 1); STG_B(1, 1, 1);
    asm volatile("s_waitcnt vmcnt(4)" ::: "memory");      // A(0),B(0) landed
    __builtin_amdgcn_s_barrier();
    RD_B(0, 0); RD_B(1, 0);                               // B(0) -> regs

    for (int kt = 0; kt < 32; ++kt) {
        const int bufc = kt & 1, bufn = bufc ^ 1;
        const int ktA = kt < 31 ? kt + 1 : 31;            // clamped duplicate at tail
        const int ktB = kt < 30 ? kt + 2 : 31;
        // ---- ph0 (mh0,nh0)
        RD_A(0, bufc);
        STG_A(0, ktA, bufn);
        __builtin_amdgcn_s_barrier();
        __builtin_amdgcn_sched_barrier(0);
        MFMA_PH(0, 0)
        __builtin_amdgcn_sched_barrier(0);
        __builtin_amdgcn_s_barrier();
        // ---- ph1 (mh0,nh1)
        asm volatile("s_waitcnt vmcnt(6)" ::: "memory");
        STG_A(1, ktA, bufn);
        __builtin_amdgcn_s_barrier();
        __builtin_amdgcn_sched_barrier(0);
        MFMA_PH(0, 1)
        __builtin_amdgcn_sched_barrier(0);
        __builtin_amdgcn_s_barrier();
        // ---- ph2 (mh1,nh0)
        asm volatile("s_waitcnt vmcnt(6)" ::: "memory");  // completes B-nh0(kt+1)
        RD_A(1, bufc);
        STG_B(0, ktB, bufc);
        __builtin_amdgcn_s_barrier();
        __builtin_amdgcn_sched_barrier(0);
        MFMA_PH(1, 0)
        __builtin_amdgcn_sched_barrier(0);
        RD_B(0, bufn);                                    // reload b[nh0] <- B(kt+1)
        __builtin_amdgcn_s_barrier();
        // ---- ph3 (mh1,nh1)
        asm volatile("s_waitcnt vmcnt(4)" ::: "memory");  // completes B-nh1(kt+1), A-mh0(kt+1)
        STG_B(1, ktB, bufc);
        __builtin_amdgcn_s_barrier();
        __builtin_amdgcn_sched_barrier(0);
        MFMA_PH(1, 1)
        __builtin_amdgcn_sched_barrier(0);
        RD_B(1, bufn);                                    // reload b[nh1] <- B(kt+1)
        __builtin_amdgcn_s_barrier();
    }

    float* Cb = SC + (size_t)b * SS * SS;
#pragma unroll
    for (int mh = 0; mh < 2; ++mh)
#pragma unroll
        for (int mi = 0; mi < 4; ++mi)
#pragma unroll
            for (int nh = 0; nh < 2; ++nh)
#pragma unroll
                for (int nj = 0; nj < 2; ++nj) {
                    const int row = i0 + wy * 128 + mh * 64 + mi * 16 + quad * 4;
                    const int col = j0 + wx * 64 + nh * 32 + nj * 16 + m16;
#pragma unroll
                    for (int reg = 0; reg < 4; ++reg)
                        Cb[(size_t)(row + reg) * SS + col] = acc[mh][mi][nh][nj][reg];
                }
#undef STG_A
#undef STG_B
#undef RD_A
#undef RD_B
#undef MFMA_PH
}

// --------------------------- softmax in place (fp32) + bf16 copy for the MFMA ctx GEMM
__global__ __launch_bounds__(256) void softmax_rows(float* __restrict__ P,
                                                    unsigned short* __restrict__ Pb) {
    const size_t row = blockIdx.x;
    float4* p4 = (float4*)(P + row * SS);
    const int tid = threadIdx.x;
    float4 v0 = p4[tid], v1 = p4[tid + 256];
    float m = fmaxf(fmaxf(fmaxf(v0.x, v0.y), fmaxf(v0.z, v0.w)),
                    fmaxf(fmaxf(v1.x, v1.y), fmaxf(v1.z, v1.w)));
#pragma unroll
    for (int off = 32; off; off >>= 1) m = fmaxf(m, __shfl_xor(m, off));
    __shared__ float red[4];
    const int wid = tid >> 6, lane = tid & 63;
    if (lane == 0) red[wid] = m;
    __syncthreads();
    m = fmaxf(fmaxf(red[0], red[1]), fmaxf(red[2], red[3]));
    v0.x = __expf(v0.x - m); v0.y = __expf(v0.y - m);
    v0.z = __expf(v0.z - m); v0.w = __expf(v0.w - m);
    v1.x = __expf(v1.x - m); v1.y = __expf(v1.y - m);
    v1.z = __expf(v1.z - m); v1.w = __expf(v1.w - m);
    float s = v0.x + v0.y + v0.z + v0.w + v1.x + v1.y + v1.z + v1.w;
#pragma unroll
    for (int off = 32; off; off >>= 1) s += __shfl_xor(s, off);
    __syncthreads();
    if (lane == 0) red[wid] = s;
    __syncthreads();
    s = red[0] + red[1] + red[2] + red[3];
    const float inv = 1.0f / s;
    v0.x *= inv; v0.y *= inv; v0.z *= inv; v0.w *= inv;
    v1.x *= inv; v1.y *= inv; v1.z *= inv; v1.w *= inv;
    p4[tid] = v0;
    p4[tid + 256] = v1;
    ushort4* b4 = (ushort4*)(Pb + row * SS);
    ushort4 u0 = { f2b(v0.x), f2b(v0.y), f2b(v0.z), f2b(v0.w) };
    ushort4 u1 = { f2b(v1.x), f2b(v1.y), f2b(v1.z), f2b(v1.w) };
    b4[tid] = u0;
    b4[tid + 256] = u1;
}

// --------------------------------- x [B,S,H] fp32 -> xT [B,H,S] bf16 (for NT ctx GEMM)
__global__ __launch_bounds__(256) void transpose_cvt(const float* __restrict__ X,
                                                     unsigned short* __restrict__ XT) {
    const int b = blockIdx.z;
    const int t0 = blockIdx.y * 64;
    const int h0 = blockIdx.x * 64;
    __shared__ float tile[64][65];
    const float* Xb = X + (size_t)b * SS * HH;
    unsigned short* Tb = XT + (size_t)b * HH * SS;
#pragma unroll
    for (int q = 0; q < 16; q++) {
        int idx = q * 256 + threadIdx.x;
        int r = idx >> 6, c = idx & 63;
        tile[r][c] = Xb[(size_t)(t0 + r) * HH + h0 + c];
    }
    __syncthreads();
#pragma unroll
    for (int q = 0; q < 16; q++) {
        int idx = q * 256 + threadIdx.x;
        int r = idx >> 6, c = idx & 63;
        Tb[(size_t)(h0 + r) * SS + t0 + c] = f2b(tile[c][r]);
    }
}

// ----------------- ctx = attn @ x  (NT bf16 MFMA, swizzled LDS)
__global__ __launch_bounds__(256) void gemm_ctx_mfma(const unsigned short* __restrict__ Ab,
                                                     const unsigned short* __restrict__ Bt,
                                                     float* __restrict__ C) {
    const int b = blockIdx.z;
    const int i0 = blockIdx.y * 128;
    const int n0 = blockIdx.x * 128;
    const unsigned short* A = Ab + (size_t)b * SS * SS;
    const unsigned short* B = Bt + (size_t)b * HH * SS;

    __shared__ __align__(16) unsigned short As[128 * 32];
    __shared__ __align__(16) unsigned short Bs[128 * 32];

    const int tid = threadIdx.x;
    const int wave = tid >> 6, lane = tid & 63;
    const int m16 = lane & 15, quad = lane >> 4;
    const int wy = wave >> 1, wx = wave & 1;
    const int rowA = tid >> 2;
    const int kq = (tid & 3) ^ ((rowA >> 1) & 3);

    f32x4 acc[4][4] = {};

    for (int k0 = 0; k0 < SS; k0 += 32) {
        async_load16(A + (size_t)(i0 + rowA) * SS + k0 + kq * 8, (char*)As + wave * 1024);
        async_load16(A + (size_t)(i0 + 64 + rowA) * SS + k0 + kq * 8, (char*)As + 4096 + wave * 1024);
        async_load16(B + (size_t)(n0 + rowA) * SS + k0 + kq * 8, (char*)Bs + wave * 1024);
        async_load16(B + (size_t)(n0 + 64 + rowA) * SS + k0 + kq * 8, (char*)Bs + 4096 + wave * 1024);
        __syncthreads();

        const int cs = quad ^ ((m16 >> 1) & 3);
        const unsigned short* pA = As + (wy * 64 + m16) * 32 + cs * 8;
        const unsigned short* pB = Bs + (wx * 64 + m16) * 32 + cs * 8;
        bf16x8 af[4], bfr[4];
#pragma unroll
        for (int r = 0; r < 4; r++) af[r] = *(const bf16x8*)(pA + r * 16 * 32);
#pragma unroll
        for (int c = 0; c < 4; c++) bfr[c] = *(const bf16x8*)(pB + c * 16 * 32);
#pragma unroll
        for (int r = 0; r < 4; r++)
#pragma unroll
            for (int c = 0; c < 4; c++)
                acc[r][c] = __builtin_amdgcn_mfma_f32_16x16x32_bf16(af[r], bfr[c], acc[r][c], 0, 0, 0);
        __syncthreads();
    }

    float* Cb = C + (size_t)b * SS * HH;
#pragma unroll
    for (int r = 0; r < 4; r++) {
        const int row = i0 + wy * 64 + r * 16 + quad * 4;
#pragma unroll
        for (int c = 0; c < 4; c++) {
            const int col = n0 + wx * 64 + c * 16 + m16;
#pragma unroll
            for (int reg = 0; reg < 4; reg++)
                Cb[(size_t)(row + reg) * HH + col] = acc[r][c][reg];
        }
    }
}

extern "C" void kernel_launch(void* const* d_in, const int* in_sizes, int n_in,
                              void* d_out, int out_size, void* d_ws, size_t ws_size,
                              hipStream_t stream) {
    const float* X = (const float*)d_in[0];   // [8,2048,1024]
    const float* W = (const float*)d_in[1];   // [1024,1024]
    float* ctx  = (float*)d_out;                            // [8,2048,1024]
    float* attn = ctx + (size_t)BB * SS * HH;               // [8,2048,2048]

    char* ws = (char*)d_ws;
    unsigned short* x_hi  = (unsigned short*)ws;                         // [0,32M)
    unsigned short* x_lo  = (unsigned short*)(ws + ((size_t)32 << 20));  // [32,64M)
    unsigned short* wt_hi = (unsigned short*)(ws + ((size_t)64 << 20));  // [64,66M)
    unsigned short* wt_lo = (unsigned short*)(ws + ((size_t)66 << 20));  // [66,68M)
    unsigned short* xT     = x_hi;                                       // after scores
    unsigned short* attn_b = x_lo;                                       // after scores

    unsigned short* xw_hi = (unsigned short*)d_out;   // dead ctx region until final GEMM
    unsigned short* xw_lo = xw_hi + (size_t)BB * SS * HH;

    dim3 blk(256);
    split_x <<<dim3(BB * SS * HH / (8 * 256)), blk, 0, stream>>>(X, x_hi, x_lo);
    split_wT<<<dim3(HH / 64, HH / 64), blk, 0, stream>>>(W, wt_hi, wt_lo);
    gemm_xw3<<<dim3(HH / 128, SS / 128, BB), blk, 0, stream>>>(x_hi, x_lo, wt_hi, wt_lo, xw_hi, xw_lo);
    gemm_sc3_8p<<<dim3(SS / 256, SS / 256, BB), dim3(512), 0, stream>>>(xw_hi, xw_lo, x_hi, x_lo, attn);
    transpose_cvt<<<dim3(HH / 64, SS / 64, BB), blk, 0, stream>>>(X, xT);
    softmax_rows <<<dim3(BB * SS), blk, 0, stream>>>(attn, attn_b);
    gemm_ctx_mfma<<<dim3(HH / 128, SS / 128, BB), blk, 0, stream>>>(attn_b, xT, ctx);
}

// Round 2
// 608.753 us; speedup vs baseline: 1.1904x; 1.1168x over previous
//
#include <hip/hip_runtime.h>
#include <hip/hip_bf16.h>

// B=8, S=2048, H=1024 — split-bf16 (fp32-emulation) MFMA pipeline.
//   x  -> x_hi/x_lo bf16; W -> Wt_hi/lo (transposed)
//   xw     = x @ W        3-pass split-bf16 MFMA -> xw_hi/lo   [8-PHASE 256², BK=32]
//   scores = xw @ x^T     3-pass split-bf16 MFMA -> attn fp32  [8-PHASE 256², BK=32]
//   attn   = softmax      in place + bf16 copy
//   ctx    = attn @ x     1-pass bf16 MFMA (NT via xT)         [8-PHASE 256², BK=64]
//
// Round 6: the verified sc3_8p schedule (T3+T4+T5: raw s_barrier, counted
// s_waitcnt vmcnt(6/6/4) never drained to 0 in the main loop, setprio around
// MFMA clusters, sched_barrier(0) pins) cloned onto gemm_xw3 (trivial clone)
// and gemm_ctx (BK=64 1-pass variant; 8-chunk XOR-by-(row&7) source swizzle,
// conflict-free at 2-way per 16-lane phase). Accumulation order per output
// element unchanged everywhere -> bit-identical results.

#define BB 8
#define SS 2048
#define HH 1024

typedef __attribute__((ext_vector_type(8))) short bf16x8;
typedef __attribute__((ext_vector_type(4))) float f32x4;

__device__ __forceinline__ void async_load16(const void* gsrc, void* ldst) {
    typedef const unsigned int __attribute__((address_space(1)))* gp_t;
    typedef unsigned int __attribute__((address_space(3)))* lp_t;
    __builtin_amdgcn_global_load_lds((gp_t)gsrc, (lp_t)ldst, 16, 0, 0);
}

__device__ __forceinline__ unsigned short f2b(float f) {
    __hip_bfloat16 h = __float2bfloat16(f);
    return *(unsigned short*)&h;
}
__device__ __forceinline__ float b2f(unsigned short u) {
    __hip_bfloat16 h = *(__hip_bfloat16*)&u;
    return __bfloat162float(h);
}

// ----------------------------------------------------------- split x -> hi/lo bf16
__global__ __launch_bounds__(256) void split_x(const float* __restrict__ X,
                                               unsigned short* __restrict__ Xh,
                                               unsigned short* __restrict__ Xl) {
    const size_t i = ((size_t)blockIdx.x * 256 + threadIdx.x) * 8;
    float4 a = *(const float4*)(X + i);
    float4 b = *(const float4*)(X + i + 4);
    ushort4 h0, h1, l0, l1;
    float v, hf;
    v = a.x; h0.x = f2b(v); hf = b2f(h0.x); l0.x = f2b(v - hf);
    v = a.y; h0.y = f2b(v); hf = b2f(h0.y); l0.y = f2b(v - hf);
    v = a.z; h0.z = f2b(v); hf = b2f(h0.z); l0.z = f2b(v - hf);
    v = a.w; h0.w = f2b(v); hf = b2f(h0.w); l0.w = f2b(v - hf);
    v = b.x; h1.x = f2b(v); hf = b2f(h1.x); l1.x = f2b(v - hf);
    v = b.y; h1.y = f2b(v); hf = b2f(h1.y); l1.y = f2b(v - hf);
    v = b.z; h1.z = f2b(v); hf = b2f(h1.z); l1.z = f2b(v - hf);
    v = b.w; h1.w = f2b(v); hf = b2f(h1.w); l1.w = f2b(v - hf);
    *(ushort4*)(Xh + i) = h0; *(ushort4*)(Xh + i + 4) = h1;
    *(ushort4*)(Xl + i) = l0; *(ushort4*)(Xl + i + 4) = l1;
}

// ------------------------------------- W [k][n] -> Wt hi/lo [n][k] (bf16 split, transpose)
__global__ __launch_bounds__(256) void split_wT(const float* __restrict__ W,
                                                unsigned short* __restrict__ Th,
                                                unsigned short* __restrict__ Tl) {
    const int k0 = blockIdx.y * 64, n0 = blockIdx.x * 64;
    __shared__ float tile[64][65];
#pragma unroll
    for (int q = 0; q < 16; q++) {
        int idx = q * 256 + threadIdx.x;
        int r = idx >> 6, c = idx & 63;
        tile[r][c] = W[(size_t)(k0 + r) * HH + n0 + c];
    }
    __syncthreads();
#pragma unroll
    for (int q = 0; q < 16; q++) {
        int idx = q * 256 + threadIdx.x;
        int r = idx >> 6, c = idx & 63;
        float v = tile[c][r];
        unsigned short h = f2b(v);
        Th[(size_t)(n0 + r) * HH + k0 + c] = h;
        Tl[(size_t)(n0 + r) * HH + k0 + c] = f2b(v - b2f(h));
    }
}

// ---------------- xw = x @ Wt^T (NT), 3-pass split-bf16, 8-phase 256² BK=32, bf16 hi/lo out
// Clone of the verified gemm_sc3_8p; B = Wt (shared across batches), epilogue re-splits.
__global__ __launch_bounds__(512, 2) void gemm_xw3_8p(const unsigned short* __restrict__ Ah,
                                                      const unsigned short* __restrict__ Al,
                                                      const unsigned short* __restrict__ Bh,
                                                      const unsigned short* __restrict__ Bl,
                                                      unsigned short* __restrict__ Ch,
                                                      unsigned short* __restrict__ Cl) {
    const int b = blockIdx.z;
    const int i0 = blockIdx.y * 256, j0 = blockIdx.x * 256;
    const unsigned short* A_h = Ah + (size_t)b * SS * HH;
    const unsigned short* A_l = Al + (size_t)b * SS * HH;
    const unsigned short* B_h = Bh;   // Wt: no batch offset
    const unsigned short* B_l = Bl;

    __shared__ __align__(16) unsigned short lds[65536];   // 128 KB

    const int tid = threadIdx.x;
    const int wave = tid >> 6, lane = tid & 63;
    const int m16 = lane & 15, quad = lane >> 4;
    const int wy = wave >> 2, wx = wave & 3;
    const int rP = tid >> 2;
    const int kq = (tid & 3) ^ ((rP >> 1) & 3);
    const int cs = quad ^ ((m16 >> 1) & 3);
    const int wt16 = wave * 1024;
    const int rowA_off = (rP & 63) + ((rP >> 6) << 7);
    const int rowB_off = ((rP >> 5) << 6) + (rP & 31);

    const size_t aOff = (size_t)(i0 + rowA_off) * HH + kq * 8;
    const size_t bOff = (size_t)(j0 + rowB_off) * HH + kq * 8;

    f32x4 acc[2][4][2][2] = {};
    bf16x8 a_h[4], a_l[4], b_h[2][2], b_l[2][2];

#define STG_A(mh, kt, buf) do { \
        const size_t o_ = aOff + (size_t)(mh) * 64 * HH + (size_t)(kt) * 32; \
        async_load16(A_h + o_, (char*)lds + ((buf) * 32768 + (mh) * 4096) * 2 + wt16); \
        async_load16(A_l + o_, (char*)lds + ((buf) * 32768 + 8192 + (mh) * 4096) * 2 + wt16); \
    } while (0)
#define STG_B(nh, kt, buf) do { \
        const size_t o_ = bOff + (size_t)(nh) * 32 * HH + (size_t)(kt) * 32; \
        async_load16(B_h + o_, (char*)lds + ((buf) * 32768 + 16384 + (nh) * 4096) * 2 + wt16); \
        async_load16(B_l + o_, (char*)lds + ((buf) * 32768 + 24576 + (nh) * 4096) * 2 + wt16); \
    } while (0)
#define RD_A(mh, buf) do { \
        const int s0_ = (buf) * 32768 + ((mh) * 128 + wy * 64 + m16) * 32 + cs * 8; \
        _Pragma("unroll") for (int mi = 0; mi < 4; ++mi) { \
            a_h[mi] = *(const bf16x8*)&lds[s0_ + mi * 512]; \
            a_l[mi] = *(const bf16x8*)&lds[8192 + s0_ + mi * 512]; \
        } } while (0)
#define RD_B(nh, buf) do { \
        const int s0_ = (buf) * 32768 + ((nh) * 128 + wx * 32 + m16) * 32 + cs * 8; \
        _Pragma("unroll") for (int nj = 0; nj < 2; ++nj) { \
            b_h[nh][nj] = *(const bf16x8*)&lds[16384 + s0_ + nj * 512]; \
            b_l[nh][nj] = *(const bf16x8*)&lds[24576 + s0_ + nj * 512]; \
        } } while (0)
#define MFMA_PH(mh, nh) \
        __builtin_amdgcn_s_setprio(1); \
        _Pragma("unroll") for (int mi = 0; mi < 4; ++mi) \
        _Pragma("unroll") for (int nj = 0; nj < 2; ++nj) { \
            acc[mh][mi][nh][nj] = __builtin_amdgcn_mfma_f32_16x16x32_bf16(a_h[mi], b_h[nh][nj], acc[mh][mi][nh][nj], 0, 0, 0); \
            acc[mh][mi][nh][nj] = __builtin_amdgcn_mfma_f32_16x16x32_bf16(a_h[mi], b_l[nh][nj], acc[mh][mi][nh][nj], 0, 0, 0); \
            acc[mh][mi][nh][nj] = __builtin_amdgcn_mfma_f32_16x16x32_bf16(a_l[mi], b_h[nh][nj], acc[mh][mi][nh][nj], 0, 0, 0); \
        } \
        __builtin_amdgcn_s_setprio(0);

    STG_A(0, 0, 0); STG_A(1, 0, 0);
    STG_B(0, 0, 0); STG_B(1, 0, 0);
    STG_B(0, 1, 1); STG_B(1, 1, 1);
    asm volatile("s_waitcnt vmcnt(4)" ::: "memory");
    __builtin_amdgcn_s_barrier();
    RD_B(0, 0); RD_B(1, 0);

    for (int kt = 0; kt < 32; ++kt) {
        const int bufc = kt & 1, bufn = bufc ^ 1;
        const int ktA = kt < 31 ? kt + 1 : 31;
        const int ktB = kt < 30 ? kt + 2 : 31;
        // ---- ph0 (mh0,nh0)
        RD_A(0, bufc);
        STG_A(0, ktA, bufn);
        __builtin_amdgcn_s_barrier();
        __builtin_amdgcn_sched_barrier(0);
        MFMA_PH(0, 0)
        __builtin_amdgcn_sched_barrier(0);
        __builtin_amdgcn_s_barrier();
        // ---- ph1 (mh0,nh1)
        asm volatile("s_waitcnt vmcnt(6)" ::: "memory");
        STG_A(1, ktA, bufn);
        __builtin_amdgcn_s_barrier();
        __builtin_amdgcn_sched_barrier(0);
        MFMA_PH(0, 1)
        __builtin_amdgcn_sched_barrier(0);
        __builtin_amdgcn_s_barrier();
        // ---- ph2 (mh1,nh0)
        asm volatile("s_waitcnt vmcnt(6)" ::: "memory");
        RD_A(1, bufc);
        STG_B(0, ktB, bufc);
        __builtin_amdgcn_s_barrier();
        __builtin_amdgcn_sched_barrier(0);
        MFMA_PH(1, 0)
        __builtin_amdgcn_sched_barrier(0);
        RD_B(0, bufn);
        __builtin_amdgcn_s_barrier();
        // ---- ph3 (mh1,nh1)
        asm volatile("s_waitcnt vmcnt(4)" ::: "memory");
        STG_B(1, ktB, bufc);
        __builtin_amdgcn_s_barrier();
        __builtin_amdgcn_sched_barrier(0);
        MFMA_PH(1, 1)
        __builtin_amdgcn_sched_barrier(0);
        RD_B(1, bufn);
        __builtin_amdgcn_s_barrier();
    }

    unsigned short* ChB = Ch + (size_t)b * SS * HH;
    unsigned short* ClB = Cl + (size_t)b * SS * HH;
#pragma unroll
    for (int mh = 0; mh < 2; ++mh)
#pragma unroll
        for (int mi = 0; mi < 4; ++mi)
#pragma unroll
            for (int nh = 0; nh < 2; ++nh)
#pragma unroll
                for (int nj = 0; nj < 2; ++nj) {
                    const int row = i0 + wy * 128 + mh * 64 + mi * 16 + quad * 4;
                    const int col = j0 + wx * 64 + nh * 32 + nj * 16 + m16;
#pragma unroll
                    for (int reg = 0; reg < 4; ++reg) {
                        float v = acc[mh][mi][nh][nj][reg];
                        unsigned short h = f2b(v);
                        ChB[(size_t)(row + reg) * HH + col] = h;
                        ClB[(size_t)(row + reg) * HH + col] = f2b(v - b2f(h));
                    }
                }
#undef STG_A
#undef STG_B
#undef RD_A
#undef RD_B
#undef MFMA_PH
}

// ---------------- scores = xw @ x^T (NT), 3-pass split-bf16 MFMA, fp32 out
// 256x256 tile, 8 waves (2M x 4N), logical BK=32, 4 phases/K-tile (verified round 5).
__global__ __launch_bounds__(512, 2) void gemm_sc3_8p(const unsigned short* __restrict__ Ah,
                                                      const unsigned short* __restrict__ Al,
                                                      const unsigned short* __restrict__ Bh,
                                                      const unsigned short* __restrict__ Bl,
                                                      float* __restrict__ SC) {
    const int b = blockIdx.z;
    const int i0 = blockIdx.y * 256, j0 = blockIdx.x * 256;
    const unsigned short* A_h = Ah + (size_t)b * SS * HH;
    const unsigned short* A_l = Al + (size_t)b * SS * HH;
    const unsigned short* B_h = Bh + (size_t)b * SS * HH;
    const unsigned short* B_l = Bl + (size_t)b * SS * HH;

    __shared__ __align__(16) unsigned short lds[65536];   // 128 KB

    const int tid = threadIdx.x;
    const int wave = tid >> 6, lane = tid & 63;
    const int m16 = lane & 15, quad = lane >> 4;
    const int wy = wave >> 2, wx = wave & 3;
    const int rP = tid >> 2;
    const int kq = (tid & 3) ^ ((rP >> 1) & 3);
    const int cs = quad ^ ((m16 >> 1) & 3);
    const int wt16 = wave * 1024;
    const int rowA_off = (rP & 63) + ((rP >> 6) << 7);
    const int rowB_off = ((rP >> 5) << 6) + (rP & 31);

    const size_t aOff = (size_t)(i0 + rowA_off) * HH + kq * 8;
    const size_t bOff = (size_t)(j0 + rowB_off) * HH + kq * 8;

    f32x4 acc[2][4][2][2] = {};
    bf16x8 a_h[4], a_l[4], b_h[2][2], b_l[2][2];

#define STG_A(mh, kt, buf) do { \
        const size_t o_ = aOff + (size_t)(mh) * 64 * HH + (size_t)(kt) * 32; \
        async_load16(A_h + o_, (char*)lds + ((buf) * 32768 + (mh) * 4096) * 2 + wt16); \
        async_load16(A_l + o_, (char*)lds + ((buf) * 32768 + 8192 + (mh) * 4096) * 2 + wt16); \
    } while (0)
#define STG_B(nh, kt, buf) do { \
        const size_t o_ = bOff + (size_t)(nh) * 32 * HH + (size_t)(kt) * 32; \
        async_load16(B_h + o_, (char*)lds + ((buf) * 32768 + 16384 + (nh) * 4096) * 2 + wt16); \
        async_load16(B_l + o_, (char*)lds + ((buf) * 32768 + 24576 + (nh) * 4096) * 2 + wt16); \
    } while (0)
#define RD_A(mh, buf) do { \
        const int s0_ = (buf) * 32768 + ((mh) * 128 + wy * 64 + m16) * 32 + cs * 8; \
        _Pragma("unroll") for (int mi = 0; mi < 4; ++mi) { \
            a_h[mi] = *(const bf16x8*)&lds[s0_ + mi * 512]; \
            a_l[mi] = *(const bf16x8*)&lds[8192 + s0_ + mi * 512]; \
        } } while (0)
#define RD_B(nh, buf) do { \
        const int s0_ = (buf) * 32768 + ((nh) * 128 + wx * 32 + m16) * 32 + cs * 8; \
        _Pragma("unroll") for (int nj = 0; nj < 2; ++nj) { \
            b_h[nh][nj] = *(const bf16x8*)&lds[16384 + s0_ + nj * 512]; \
            b_l[nh][nj] = *(const bf16x8*)&lds[24576 + s0_ + nj * 512]; \
        } } while (0)
#define MFMA_PH(mh, nh) \
        __builtin_amdgcn_s_setprio(1); \
        _Pragma("unroll") for (int mi = 0; mi < 4; ++mi) \
        _Pragma("unroll") for (int nj = 0; nj < 2; ++nj) { \
            acc[mh][mi][nh][nj] = __builtin_amdgcn_mfma_f32_16x16x32_bf16(a_h[mi], b_h[nh][nj], acc[mh][mi][nh][nj], 0, 0, 0); \
            acc[mh][mi][nh][nj] = __builtin_amdgcn_mfma_f32_16x16x32_bf16(a_h[mi], b_l[nh][nj], acc[mh][mi][nh][nj], 0, 0, 0); \
            acc[mh][mi][nh][nj] = __builtin_amdgcn_mfma_f32_16x16x32_bf16(a_l[mi], b_h[nh][nj], acc[mh][mi][nh][nj], 0, 0, 0); \
        } \
        __builtin_amdgcn_s_setprio(0);

    STG_A(0, 0, 0); STG_A(1, 0, 0);
    STG_B(0, 0, 0); STG_B(1, 0, 0);
    STG_B(0, 1, 1); STG_B(1, 1, 1);
    asm volatile("s_waitcnt vmcnt(4)" ::: "memory");
    __builtin_amdgcn_s_barrier();
    RD_B(0, 0); RD_B(1, 0);

    for (int kt = 0; kt < 32; ++kt) {
        const int bufc = kt & 1, bufn = bufc ^ 1;
        const int ktA = kt < 31 ? kt + 1 : 31;
        const int ktB = kt < 30 ? kt + 2 : 31;
        // ---- ph0 (mh0,nh0)
        RD_A(0, bufc);
        STG_A(0, ktA, bufn);
        __builtin_amdgcn_s_barrier();
        __builtin_amdgcn_sched_barrier(0);
        MFMA_PH(0, 0)
        __builtin_amdgcn_sched_barrier(0);
        __builtin_amdgcn_s_barrier();
        // ---- ph1 (mh0,nh1)
        asm volatile("s_waitcnt vmcnt(6)" ::: "memory");
        STG_A(1, ktA, bufn);
        __builtin_amdgcn_s_barrier();
        __builtin_amdgcn_sched_barrier(0);
        MFMA_PH(0, 1)
        __builtin_amdgcn_sched_barrier(0);
        __builtin_amdgcn_s_barrier();
        // ---- ph2 (mh1,nh0)
        asm volatile("s_waitcnt vmcnt(6)" ::: "memory");
        RD_A(1, bufc);
        STG_B(0, ktB, bufc);
        __builtin_amdgcn_s_barrier();
        __builtin_amdgcn_sched_barrier(0);
        MFMA_PH(1, 0)
        __builtin_amdgcn_sched_barrier(0);
        RD_B(0, bufn);
        __builtin_amdgcn_s_barrier();
        // ---- ph3 (mh1,nh1)
        asm volatile("s_waitcnt vmcnt(4)" ::: "memory");
        STG_B(1, ktB, bufc);
        __builtin_amdgcn_s_barrier();
        __builtin_amdgcn_sched_barrier(0);
        MFMA_PH(1, 1)
        __builtin_amdgcn_sched_barrier(0);
        RD_B(1, bufn);
        __builtin_amdgcn_s_barrier();
    }

    float* Cb = SC + (size_t)b * SS * SS;
#pragma unroll
    for (int mh = 0; mh < 2; ++mh)
#pragma unroll
        for (int mi = 0; mi < 4; ++mi)
#pragma unroll
            for (int nh = 0; nh < 2; ++nh)
#pragma unroll
                for (int nj = 0; nj < 2; ++nj) {
                    const int row = i0 + wy * 128 + mh * 64 + mi * 16 + quad * 4;
                    const int col = j0 + wx * 64 + nh * 32 + nj * 16 + m16;
#pragma unroll
                    for (int reg = 0; reg < 4; ++reg)
                        Cb[(size_t)(row + reg) * SS + col] = acc[mh][mi][nh][nj][reg];
                }
#undef STG_A
#undef STG_B
#undef RD_A
#undef RD_B
#undef MFMA_PH
}

// --------------------------- softmax in place (fp32) + bf16 copy for the MFMA ctx GEMM
__global__ __launch_bounds__(256) void softmax_rows(float* __restrict__ P,
                                                    unsigned short* __restrict__ Pb) {
    const size_t row = blockIdx.x;
    float4* p4 = (float4*)(P + row * SS);
    const int tid = threadIdx.x;
    float4 v0 = p4[tid], v1 = p4[tid + 256];
    float m = fmaxf(fmaxf(fmaxf(v0.x, v0.y), fmaxf(v0.z, v0.w)),
                    fmaxf(fmaxf(v1.x, v1.y), fmaxf(v1.z, v1.w)));
#pragma unroll
    for (int off = 32; off; off >>= 1) m = fmaxf(m, __shfl_xor(m, off));
    __shared__ float red[4];
    const int wid = tid >> 6, lane = tid & 63;
    if (lane == 0) red[wid] = m;
    __syncthreads();
    m = fmaxf(fmaxf(red[0], red[1]), fmaxf(red[2], red[3]));
    v0.x = __expf(v0.x - m); v0.y = __expf(v0.y - m);
    v0.z = __expf(v0.z - m); v0.w = __expf(v0.w - m);
    v1.x = __expf(v1.x - m); v1.y = __expf(v1.y - m);
    v1.z = __expf(v1.z - m); v1.w = __expf(v1.w - m);
    float s = v0.x + v0.y + v0.z + v0.w + v1.x + v1.y + v1.z + v1.w;
#pragma unroll
    for (int off = 32; off; off >>= 1) s += __shfl_xor(s, off);
    __syncthreads();
    if (lane == 0) red[wid] = s;
    __syncthreads();
    s = red[0] + red[1] + red[2] + red[3];
    const float inv = 1.0f / s;
    v0.x *= inv; v0.y *= inv; v0.z *= inv; v0.w *= inv;
    v1.x *= inv; v1.y *= inv; v1.z *= inv; v1.w *= inv;
    p4[tid] = v0;
    p4[tid + 256] = v1;
    ushort4* b4 = (ushort4*)(Pb + row * SS);
    ushort4 u0 = { f2b(v0.x), f2b(v0.y), f2b(v0.z), f2b(v0.w) };
    ushort4 u1 = { f2b(v1.x), f2b(v1.y), f2b(v1.z), f2b(v1.w) };
    b4[tid] = u0;
    b4[tid + 256] = u1;
}

// --------------------------------- x [B,S,H] fp32 -> xT [B,H,S] bf16 (for NT ctx GEMM)
__global__ __launch_bounds__(256) void transpose_cvt(const float* __restrict__ X,
                                                     unsigned short* __restrict__ XT) {
    const int b = blockIdx.z;
    const int t0 = blockIdx.y * 64;
    const int h0 = blockIdx.x * 64;
    __shared__ float tile[64][65];
    const float* Xb = X + (size_t)b * SS * HH;
    unsigned short* Tb = XT + (size_t)b * HH * SS;
#pragma unroll
    for (int q = 0; q < 16; q++) {
        int idx = q * 256 + threadIdx.x;
        int r = idx >> 6, c = idx & 63;
        tile[r][c] = Xb[(size_t)(t0 + r) * HH + h0 + c];
    }
    __syncthreads();
#pragma unroll
    for (int q = 0; q < 16; q++) {
        int idx = q * 256 + threadIdx.x;
        int r = idx >> 6, c = idx & 63;
        Tb[(size_t)(h0 + r) * SS + t0 + c] = f2b(tile[c][r]);
    }
}

// ----------------- ctx = attn @ x (NT bf16 MFMA), 8-phase 256² tile, BK=64, 1-pass
// A = attn_b [S,S] bf16, B = xT [H,S] bf16. LDS: 2 bufs x (A 32K + B 32K) = 128 KB.
// Per row 64 bf16 = 8 chunks of 16B; source swizzle chunk c' = (tid&7)^((tid>>3)&7);
// read slot = (ks*4+quad)^(row&7) — 2-way per 16-lane phase = conflict-free.
// A call(mh,h): LDS q-row mh*128+h*64+(tid>>3) holds A row mh*64+h*128+(tid>>3).
// B call(nh,h): LDS p-row (in nh sub) h*64+(tid>>3) holds B row (p>>5)*64+nh*32+(p&31).
// Same prologue/vmcnt(6/6/4) queue arithmetic as gemm_sc3_8p (2 issues/phase).
__global__ __launch_bounds__(512, 2) void gemm_ctx_8p(const unsigned short* __restrict__ Ab,
                                                      const unsigned short* __restrict__ Bt,
                                                      float* __restrict__ C) {
    const int b = blockIdx.z;
    const int i0 = blockIdx.y * 256, n0 = blockIdx.x * 256;
    const unsigned short* A = Ab + (size_t)b * SS * SS;
    const unsigned short* B = Bt + (size_t)b * HH * SS;

    __shared__ __align__(16) unsigned short lds[65536];   // 128 KB

    const int tid = threadIdx.x;
    const int wave = tid >> 6, lane = tid & 63;
    const int m16 = lane & 15, quad = lane >> 4;
    const int m7 = m16 & 7;
    const int wy = wave >> 2, wx = wave & 3;
    const int rA8 = tid >> 3;
    const int c8 = (tid & 7) ^ (rA8 & 7);
    const int wt16 = wave * 1024;
    const int sl0 = (quad ^ m7) * 8;          // ushort offset, ks=0 slot
    const int sl1 = ((quad + 4) ^ m7) * 8;    // ks=1 slot

    const size_t aSrc = (size_t)(i0 + rA8) * SS + c8 * 8;
    const size_t bSrc = (size_t)(n0 + ((rA8 >> 5) << 6) + (rA8 & 31)) * SS + c8 * 8;

    f32x4 acc[2][4][2][2] = {};               // [mh][mi][nh][nj]
    bf16x8 a[4][2], bb[2][2][2];              // a[mi][ks], bb[nh][nj][ks]

#define CSTG_A(mh, h, kt, buf) \
    async_load16(A + aSrc + (size_t)((mh) * 64 + (h) * 128) * SS + (size_t)(kt) * 64, \
                 (char*)lds + (buf) * 65536 + (mh) * 16384 + (h) * 8192 + wt16)
#define CSTG_B(nh, h, kt, buf) \
    async_load16(B + bSrc + (size_t)((h) * 128 + (nh) * 32) * SS + (size_t)(kt) * 64, \
                 (char*)lds + (buf) * 65536 + 32768 + (nh) * 16384 + (h) * 8192 + wt16)
#define CRD_A(mh, buf) do { \
        const int r0_ = (buf) * 32768 + ((mh) * 128 + wy * 64 + m16) * 64; \
        _Pragma("unroll") for (int mi = 0; mi < 4; ++mi) { \
            a[mi][0] = *(const bf16x8*)&lds[r0_ + mi * 1024 + sl0]; \
            a[mi][1] = *(const bf16x8*)&lds[r0_ + mi * 1024 + sl1]; \
        } } while (0)
#define CRD_B(nh, buf) do { \
        const int r0_ = (buf) * 32768 + 16384 + (nh) * 8192 + (wx * 32 + m16) * 64; \
        _Pragma("unroll") for (int nj = 0; nj < 2; ++nj) { \
            bb[nh][nj][0] = *(const bf16x8*)&lds[r0_ + nj * 1024 + sl0]; \
            bb[nh][nj][1] = *(const bf16x8*)&lds[r0_ + nj * 1024 + sl1]; \
        } } while (0)
#define CMFMA(mh, nh) \
        __builtin_amdgcn_s_setprio(1); \
        _Pragma("unroll") for (int mi = 0; mi < 4; ++mi) \
        _Pragma("unroll") for (int nj = 0; nj < 2; ++nj) { \
            acc[mh][mi][nh][nj] = __builtin_amdgcn_mfma_f32_16x16x32_bf16(a[mi][0], bb[nh][nj][0], acc[mh][mi][nh][nj], 0, 0, 0); \
            acc[mh][mi][nh][nj] = __builtin_amdgcn_mfma_f32_16x16x32_bf16(a[mi][1], bb[nh][nj][1], acc[mh][mi][nh][nj], 0, 0, 0); \
        } \
        __builtin_amdgcn_s_setprio(0);

    CSTG_A(0, 0, 0, 0); CSTG_A(0, 1, 0, 0);
    CSTG_A(1, 0, 0, 0); CSTG_A(1, 1, 0, 0);
    CSTG_B(0, 0, 0, 0); CSTG_B(0, 1, 0, 0);
    CSTG_B(1, 0, 0, 0); CSTG_B(1, 1, 0, 0);
    CSTG_B(0, 0, 1, 1); CSTG_B(0, 1, 1, 1);
    CSTG_B(1, 0, 1, 1); CSTG_B(1, 1, 1, 1);
    asm volatile("s_waitcnt vmcnt(4)" ::: "memory");
    __builtin_amdgcn_s_barrier();
    CRD_B(0, 0); CRD_B(1, 0);

    for (int kt = 0; kt < 32; ++kt) {
        const int bufc = kt & 1, bufn = bufc ^ 1;
        const int ktA = kt < 31 ? kt + 1 : 31;
        const int ktB = kt < 30 ? kt + 2 : 31;
        // ---- ph0 (mh0,nh0)
        CRD_A(0, bufc);
        CSTG_A(0, 0, ktA, bufn); CSTG_A(0, 1, ktA, bufn);
        __builtin_amdgcn_s_barrier();
        __builtin_amdgcn_sched_barrier(0);
        CMFMA(0, 0)
        __builtin_amdgcn_sched_barrier(0);
        __builtin_amdgcn_s_barrier();
        // ---- ph1 (mh0,nh1)
        asm volatile("s_waitcnt vmcnt(6)" ::: "memory");
        CSTG_A(1, 0, ktA, bufn); CSTG_A(1, 1, ktA, bufn);
        __builtin_amdgcn_s_barrier();
        __builtin_amdgcn_sched_barrier(0);
        CMFMA(0, 1)
        __builtin_amdgcn_sched_barrier(0);
        __builtin_amdgcn_s_barrier();
        // ---- ph2 (mh1,nh0)
        asm volatile("s_waitcnt vmcnt(6)" ::: "memory");
        CRD_A(1, bufc);
        CSTG_B(0, 0, ktB, bufc); CSTG_B(0, 1, ktB, bufc);
        __builtin_amdgcn_s_barrier();
        __builtin_amdgcn_sched_barrier(0);
        CMFMA(1, 0)
        __builtin_amdgcn_sched_barrier(0);
        CRD_B(0, bufn);
        __builtin_amdgcn_s_barrier();
        // ---- ph3 (mh1,nh1)
        asm volatile("s_waitcnt vmcnt(4)" ::: "memory");
        CSTG_B(1, 0, ktB, bufc); CSTG_B(1, 1, ktB, bufc);
        __builtin_amdgcn_s_barrier();
        __builtin_amdgcn_sched_barrier(0);
        CMFMA(1, 1)
        __builtin_amdgcn_sched_barrier(0);
        CRD_B(1, bufn);
        __builtin_amdgcn_s_barrier();
    }

    float* Cb = C + (size_t)b * SS * HH;
#pragma unroll
    for (int mh = 0; mh < 2; ++mh)
#pragma unroll
        for (int mi = 0; mi < 4; ++mi)
#pragma unroll
            for (int nh = 0; nh < 2; ++nh)
#pragma unroll
                for (int nj = 0; nj < 2; ++nj) {
                    const int row = i0 + wy * 128 + mh * 64 + mi * 16 + quad * 4;
                    const int col = n0 + wx * 64 + nh * 32 + nj * 16 + m16;
#pragma unroll
                    for (int reg = 0; reg < 4; ++reg)
                        Cb[(size_t)(row + reg) * HH + col] = acc[mh][mi][nh][nj][reg];
                }
#undef CSTG_A
#undef CSTG_B
#undef CRD_A
#undef CRD_B
#undef CMFMA
}

extern "C" void kernel_launch(void* const* d_in, const int* in_sizes, int n_in,
                              void* d_out, int out_size, void* d_ws, size_t ws_size,
                              hipStream_t stream) {
    const float* X = (const float*)d_in[0];   // [8,2048,1024]
    const float* W = (const float*)d_in[1];   // [1024,1024]
    float* ctx  = (float*)d_out;                            // [8,2048,1024]
    float* attn = ctx + (size_t)BB * SS * HH;               // [8,2048,2048]

    char* ws = (char*)d_ws;
    unsigned short* x_hi  = (unsigned short*)ws;                         // [0,32M)
    unsigned short* x_lo  = (unsigned short*)(ws + ((size_t)32 << 20));  // [32,64M)
    unsigned short* wt_hi = (unsigned short*)(ws + ((size_t)64 << 20));  // [64,66M)
    unsigned short* wt_lo = (unsigned short*)(ws + ((size_t)66 << 20));  // [66,68M)
    unsigned short* xT     = x_hi;                                       // after scores
    unsigned short* attn_b = x_lo;                                       // after scores

    unsigned short* xw_hi = (unsigned short*)d_out;   // dead ctx region until final GEMM
    unsigned short* xw_lo = xw_hi + (size_t)BB * SS * HH;

    dim3 blk(256);
    split_x <<<dim3(BB * SS * HH / (8 * 256)), blk, 0, stream>>>(X, x_hi, x_lo);
    split_wT<<<dim3(HH / 64, HH / 64), blk, 0, stream>>>(W, wt_hi, wt_lo);
    gemm_xw3_8p<<<dim3(HH / 256, SS / 256, BB), dim3(512), 0, stream>>>(x_hi, x_lo, wt_hi, wt_lo, xw_hi, xw_lo);
    gemm_sc3_8p<<<dim3(SS / 256, SS / 256, BB), dim3(512), 0, stream>>>(xw_hi, xw_lo, x_hi, x_lo, attn);
    transpose_cvt<<<dim3(HH / 64, SS / 64, BB), blk, 0, stream>>>(X, xT);
    softmax_rows <<<dim3(BB * SS), blk, 0, stream>>>(attn, attn_b);
    gemm_ctx_8p<<<dim3(HH / 256, SS / 256, BB), dim3(512), 0, stream>>>(attn_b, xT, ctx);
}

// Round 4
// 602.509 us; speedup vs baseline: 1.2027x; 1.0104x over previous
//
#include <hip/hip_runtime.h>
#include <hip/hip_bf16.h>

// B=8, S=2048, H=1024 — split-bf16 (fp32-emulation) MFMA pipeline.
//   x  -> x_hi/x_lo bf16; W -> Wt_hi/lo (transposed)
//   xw     = x @ W        3-pass split-bf16 MFMA -> xw_hi/lo   [8-PHASE 256², BK=32]
//   scores = xw @ x^T     3-pass split-bf16 MFMA -> attn fp32  [8-PHASE 256², BK=32]
//   attn   = softmax      in place + bf16 copy
//   ctx    = attn @ x     1-pass bf16 MFMA (NT via xT)         [8-PHASE 256², BK=64]
//
// Round 8 (= round 7 resubmit after infra failure): fold the LDS-read slots
// into the MFMA clusters. Previously each phase was {RD/STG | barrier | MFMA |
// barrier} — ds_reads serialized with MFMA (LDS port idle during MFMA, matrix
// pipe idle during reads; MfmaUtil capped ~53%). Now ALL fragment reads are
// post-MFMA in-cluster (the pattern RD_B already used): old ph0-pre RD_A(0) ->
// ph3-post (A(kt+1)-mh0 retired by ph3's existing vmcnt(4)); old ph2-pre
// RD_A(1) -> ph1-post (A(kt)-mh1 retired by ph1's existing vmcnt(6)).
// vmcnt values, staging schedule, phase order, barriers: unchanged.
// Zero register growth. Bit-identical accumulation order.

#define BB 8
#define SS 2048
#define HH 1024

typedef __attribute__((ext_vector_type(8))) short bf16x8;
typedef __attribute__((ext_vector_type(4))) float f32x4;

__device__ __forceinline__ void async_load16(const void* gsrc, void* ldst) {
    typedef const unsigned int __attribute__((address_space(1)))* gp_t;
    typedef unsigned int __attribute__((address_space(3)))* lp_t;
    __builtin_amdgcn_global_load_lds((gp_t)gsrc, (lp_t)ldst, 16, 0, 0);
}

__device__ __forceinline__ unsigned short f2b(float f) {
    __hip_bfloat16 h = __float2bfloat16(f);
    return *(unsigned short*)&h;
}
__device__ __forceinline__ float b2f(unsigned short u) {
    __hip_bfloat16 h = *(__hip_bfloat16*)&u;
    return __bfloat162float(h);
}

// ----------------------------------------------------------- split x -> hi/lo bf16
__global__ __launch_bounds__(256) void split_x(const float* __restrict__ X,
                                               unsigned short* __restrict__ Xh,
                                               unsigned short* __restrict__ Xl) {
    const size_t i = ((size_t)blockIdx.x * 256 + threadIdx.x) * 8;
    float4 a = *(const float4*)(X + i);
    float4 b = *(const float4*)(X + i + 4);
    ushort4 h0, h1, l0, l1;
    float v, hf;
    v = a.x; h0.x = f2b(v); hf = b2f(h0.x); l0.x = f2b(v - hf);
    v = a.y; h0.y = f2b(v); hf = b2f(h0.y); l0.y = f2b(v - hf);
    v = a.z; h0.z = f2b(v); hf = b2f(h0.z); l0.z = f2b(v - hf);
    v = a.w; h0.w = f2b(v); hf = b2f(h0.w); l0.w = f2b(v - hf);
    v = b.x; h1.x = f2b(v); hf = b2f(h1.x); l1.x = f2b(v - hf);
    v = b.y; h1.y = f2b(v); hf = b2f(h1.y); l1.y = f2b(v - hf);
    v = b.z; h1.z = f2b(v); hf = b2f(h1.z); l1.z = f2b(v - hf);
    v = b.w; h1.w = f2b(v); hf = b2f(h1.w); l1.w = f2b(v - hf);
    *(ushort4*)(Xh + i) = h0; *(ushort4*)(Xh + i + 4) = h1;
    *(ushort4*)(Xl + i) = l0; *(ushort4*)(Xl + i + 4) = l1;
}

// ------------------------------------- W [k][n] -> Wt hi/lo [n][k] (bf16 split, transpose)
__global__ __launch_bounds__(256) void split_wT(const float* __restrict__ W,
                                                unsigned short* __restrict__ Th,
                                                unsigned short* __restrict__ Tl) {
    const int k0 = blockIdx.y * 64, n0 = blockIdx.x * 64;
    __shared__ float tile[64][65];
#pragma unroll
    for (int q = 0; q < 16; q++) {
        int idx = q * 256 + threadIdx.x;
        int r = idx >> 6, c = idx & 63;
        tile[r][c] = W[(size_t)(k0 + r) * HH + n0 + c];
    }
    __syncthreads();
#pragma unroll
    for (int q = 0; q < 16; q++) {
        int idx = q * 256 + threadIdx.x;
        int r = idx >> 6, c = idx & 63;
        float v = tile[c][r];
        unsigned short h = f2b(v);
        Th[(size_t)(n0 + r) * HH + k0 + c] = h;
        Tl[(size_t)(n0 + r) * HH + k0 + c] = f2b(v - b2f(h));
    }
}

// Shared 8-phase split-bf16 GEMM body (NT, 256² tile, BK=32, 2M x 4N waves).
// Phase layout (reads all post-MFMA, in-cluster):
//   ph0 (0,0): STG_A0(kt+1)                         | MFMA
//   ph1 (0,1): vmcnt(6) STG_A1(kt+1)                | MFMA | RD_A1(bufc)
//   ph2 (1,0): vmcnt(6) STG_B0(kt+2)                | MFMA | RD_B0(bufn)
//   ph3 (1,1): vmcnt(4) STG_B1(kt+2)                | MFMA | RD_B1(bufn) RD_A0(bufn)
#define SPLIT3_8P_BODY(A_h, A_l, B_h, B_l)                                          \
    __shared__ __align__(16) unsigned short lds[65536];                             \
    const int tid = threadIdx.x;                                                    \
    const int wave = tid >> 6, lane = tid & 63;                                     \
    const int m16 = lane & 15, quad = lane >> 4;                                    \
    const int wy = wave >> 2, wx = wave & 3;                                        \
    const int rP = tid >> 2;                                                        \
    const int kq = (tid & 3) ^ ((rP >> 1) & 3);                                     \
    const int cs = quad ^ ((m16 >> 1) & 3);                                         \
    const int wt16 = wave * 1024;                                                   \
    const int rowA_off = (rP & 63) + ((rP >> 6) << 7);                              \
    const int rowB_off = ((rP >> 5) << 6) + (rP & 31);                              \
    const size_t aOff = (size_t)(i0 + rowA_off) * HH + kq * 8;                      \
    const size_t bOff = (size_t)(j0 + rowB_off) * HH + kq * 8;                      \
    f32x4 acc[2][4][2][2] = {};                                                     \
    bf16x8 a_h[4], a_l[4], b_h[2][2], b_l[2][2];                                    \
    STG_A(0, 0, 0); STG_A(1, 0, 0);                                                 \
    STG_B(0, 0, 0); STG_B(1, 0, 0);                                                 \
    STG_B(0, 1, 1); STG_B(1, 1, 1);                                                 \
    asm volatile("s_waitcnt vmcnt(4)" ::: "memory");                                \
    __builtin_amdgcn_s_barrier();                                                   \
    RD_A(0, 0); RD_B(0, 0); RD_B(1, 0);                                             \
    for (int kt = 0; kt < 32; ++kt) {                                               \
        const int bufc = kt & 1, bufn = bufc ^ 1;                                   \
        const int ktA = kt < 31 ? kt + 1 : 31;                                      \
        const int ktB = kt < 30 ? kt + 2 : 31;                                      \
        /* ---- ph0 (mh0,nh0) */                                                    \
        STG_A(0, ktA, bufn);                                                        \
        __builtin_amdgcn_s_barrier();                                               \
        __builtin_amdgcn_sched_barrier(0);                                          \
        MFMA_PH(0, 0)                                                               \
        __builtin_amdgcn_sched_barrier(0);                                          \
        __builtin_amdgcn_s_barrier();                                               \
        /* ---- ph1 (mh0,nh1) */                                                    \
        asm volatile("s_waitcnt vmcnt(6)" ::: "memory");                            \
        STG_A(1, ktA, bufn);                                                        \
        __builtin_amdgcn_s_barrier();                                               \
        __builtin_amdgcn_sched_barrier(0);                                          \
        MFMA_PH(0, 1)                                                               \
        __builtin_amdgcn_sched_barrier(0);                                          \
        RD_A(1, bufc);                                                              \
        __builtin_amdgcn_s_barrier();                                               \
        /* ---- ph2 (mh1,nh0) */                                                    \
        asm volatile("s_waitcnt vmcnt(6)" ::: "memory");                            \
        STG_B(0, ktB, bufc);                                                        \
        __builtin_amdgcn_s_barrier();                                               \
        __builtin_amdgcn_sched_barrier(0);                                          \
        MFMA_PH(1, 0)                                                               \
        __builtin_amdgcn_sched_barrier(0);                                          \
        RD_B(0, bufn);                                                              \
        __builtin_amdgcn_s_barrier();                                               \
        /* ---- ph3 (mh1,nh1) */                                                    \
        asm volatile("s_waitcnt vmcnt(4)" ::: "memory");                            \
        STG_B(1, ktB, bufc);                                                        \
        __builtin_amdgcn_s_barrier();                                               \
        __builtin_amdgcn_sched_barrier(0);                                          \
        MFMA_PH(1, 1)                                                               \
        __builtin_amdgcn_sched_barrier(0);                                          \
        RD_B(1, bufn);                                                              \
        RD_A(0, bufn);                                                              \
        __builtin_amdgcn_s_barrier();                                               \
    }

#define STG_A(mh, kt, buf) do { \
        const size_t o_ = aOff + (size_t)(mh) * 64 * HH + (size_t)(kt) * 32; \
        async_load16(A_h + o_, (char*)lds + ((buf) * 32768 + (mh) * 4096) * 2 + wt16); \
        async_load16(A_l + o_, (char*)lds + ((buf) * 32768 + 8192 + (mh) * 4096) * 2 + wt16); \
    } while (0)
#define STG_B(nh, kt, buf) do { \
        const size_t o_ = bOff + (size_t)(nh) * 32 * HH + (size_t)(kt) * 32; \
        async_load16(B_h + o_, (char*)lds + ((buf) * 32768 + 16384 + (nh) * 4096) * 2 + wt16); \
        async_load16(B_l + o_, (char*)lds + ((buf) * 32768 + 24576 + (nh) * 4096) * 2 + wt16); \
    } while (0)
#define RD_A(mh, buf) do { \
        const int s0_ = (buf) * 32768 + ((mh) * 128 + wy * 64 + m16) * 32 + cs * 8; \
        _Pragma("unroll") for (int mi = 0; mi < 4; ++mi) { \
            a_h[mi] = *(const bf16x8*)&lds[s0_ + mi * 512]; \
            a_l[mi] = *(const bf16x8*)&lds[8192 + s0_ + mi * 512]; \
        } } while (0)
#define RD_B(nh, buf) do { \
        const int s0_ = (buf) * 32768 + ((nh) * 128 + wx * 32 + m16) * 32 + cs * 8; \
        _Pragma("unroll") for (int nj = 0; nj < 2; ++nj) { \
            b_h[nh][nj] = *(const bf16x8*)&lds[16384 + s0_ + nj * 512]; \
            b_l[nh][nj] = *(const bf16x8*)&lds[24576 + s0_ + nj * 512]; \
        } } while (0)
#define MFMA_PH(mh, nh) \
        __builtin_amdgcn_s_setprio(1); \
        _Pragma("unroll") for (int mi = 0; mi < 4; ++mi) \
        _Pragma("unroll") for (int nj = 0; nj < 2; ++nj) { \
            acc[mh][mi][nh][nj] = __builtin_amdgcn_mfma_f32_16x16x32_bf16(a_h[mi], b_h[nh][nj], acc[mh][mi][nh][nj], 0, 0, 0); \
            acc[mh][mi][nh][nj] = __builtin_amdgcn_mfma_f32_16x16x32_bf16(a_h[mi], b_l[nh][nj], acc[mh][mi][nh][nj], 0, 0, 0); \
            acc[mh][mi][nh][nj] = __builtin_amdgcn_mfma_f32_16x16x32_bf16(a_l[mi], b_h[nh][nj], acc[mh][mi][nh][nj], 0, 0, 0); \
        } \
        __builtin_amdgcn_s_setprio(0);

// ---------------- xw = x @ Wt^T (NT), 3-pass split-bf16, 8-phase 256² BK=32, bf16 hi/lo out
__global__ __launch_bounds__(512, 2) void gemm_xw3_8p(const unsigned short* __restrict__ Ah,
                                                      const unsigned short* __restrict__ Al,
                                                      const unsigned short* __restrict__ Bh,
                                                      const unsigned short* __restrict__ Bl,
                                                      unsigned short* __restrict__ Ch,
                                                      unsigned short* __restrict__ Cl) {
    const int b = blockIdx.z;
    const int i0 = blockIdx.y * 256, j0 = blockIdx.x * 256;
    const unsigned short* A_h = Ah + (size_t)b * SS * HH;
    const unsigned short* A_l = Al + (size_t)b * SS * HH;
    const unsigned short* B_h = Bh;   // Wt: no batch offset
    const unsigned short* B_l = Bl;

    SPLIT3_8P_BODY(A_h, A_l, B_h, B_l)

    unsigned short* ChB = Ch + (size_t)b * SS * HH;
    unsigned short* ClB = Cl + (size_t)b * SS * HH;
#pragma unroll
    for (int mh = 0; mh < 2; ++mh)
#pragma unroll
        for (int mi = 0; mi < 4; ++mi)
#pragma unroll
            for (int nh = 0; nh < 2; ++nh)
#pragma unroll
                for (int nj = 0; nj < 2; ++nj) {
                    const int row = i0 + wy * 128 + mh * 64 + mi * 16 + quad * 4;
                    const int col = j0 + wx * 64 + nh * 32 + nj * 16 + m16;
#pragma unroll
                    for (int reg = 0; reg < 4; ++reg) {
                        float v = acc[mh][mi][nh][nj][reg];
                        unsigned short h = f2b(v);
                        ChB[(size_t)(row + reg) * HH + col] = h;
                        ClB[(size_t)(row + reg) * HH + col] = f2b(v - b2f(h));
                    }
                }
}

// ---------------- scores = xw @ x^T (NT), 3-pass split-bf16 MFMA, fp32 out
__global__ __launch_bounds__(512, 2) void gemm_sc3_8p(const unsigned short* __restrict__ Ah,
                                                      const unsigned short* __restrict__ Al,
                                                      const unsigned short* __restrict__ Bh,
                                                      const unsigned short* __restrict__ Bl,
                                                      float* __restrict__ SC) {
    const int b = blockIdx.z;
    const int i0 = blockIdx.y * 256, j0 = blockIdx.x * 256;
    const unsigned short* A_h = Ah + (size_t)b * SS * HH;
    const unsigned short* A_l = Al + (size_t)b * SS * HH;
    const unsigned short* B_h = Bh + (size_t)b * SS * HH;
    const unsigned short* B_l = Bl + (size_t)b * SS * HH;

    SPLIT3_8P_BODY(A_h, A_l, B_h, B_l)

    float* Cb = SC + (size_t)b * SS * SS;
#pragma unroll
    for (int mh = 0; mh < 2; ++mh)
#pragma unroll
        for (int mi = 0; mi < 4; ++mi)
#pragma unroll
            for (int nh = 0; nh < 2; ++nh)
#pragma unroll
                for (int nj = 0; nj < 2; ++nj) {
                    const int row = i0 + wy * 128 + mh * 64 + mi * 16 + quad * 4;
                    const int col = j0 + wx * 64 + nh * 32 + nj * 16 + m16;
#pragma unroll
                    for (int reg = 0; reg < 4; ++reg)
                        Cb[(size_t)(row + reg) * SS + col] = acc[mh][mi][nh][nj][reg];
                }
}

#undef STG_A
#undef STG_B
#undef RD_A
#undef RD_B
#undef MFMA_PH
#undef SPLIT3_8P_BODY

// --------------------------- softmax in place (fp32) + bf16 copy for the MFMA ctx GEMM
__global__ __launch_bounds__(256) void softmax_rows(float* __restrict__ P,
                                                    unsigned short* __restrict__ Pb) {
    const size_t row = blockIdx.x;
    float4* p4 = (float4*)(P + row * SS);
    const int tid = threadIdx.x;
    float4 v0 = p4[tid], v1 = p4[tid + 256];
    float m = fmaxf(fmaxf(fmaxf(v0.x, v0.y), fmaxf(v0.z, v0.w)),
                    fmaxf(fmaxf(v1.x, v1.y), fmaxf(v1.z, v1.w)));
#pragma unroll
    for (int off = 32; off; off >>= 1) m = fmaxf(m, __shfl_xor(m, off));
    __shared__ float red[4];
    const int wid = tid >> 6, lane = tid & 63;
    if (lane == 0) red[wid] = m;
    __syncthreads();
    m = fmaxf(fmaxf(red[0], red[1]), fmaxf(red[2], red[3]));
    v0.x = __expf(v0.x - m); v0.y = __expf(v0.y - m);
    v0.z = __expf(v0.z - m); v0.w = __expf(v0.w - m);
    v1.x = __expf(v1.x - m); v1.y = __expf(v1.y - m);
    v1.z = __expf(v1.z - m); v1.w = __expf(v1.w - m);
    float s = v0.x + v0.y + v0.z + v0.w + v1.x + v1.y + v1.z + v1.w;
#pragma unroll
    for (int off = 32; off; off >>= 1) s += __shfl_xor(s, off);
    __syncthreads();
    if (lane == 0) red[wid] = s;
    __syncthreads();
    s = red[0] + red[1] + red[2] + red[3];
    const float inv = 1.0f / s;
    v0.x *= inv; v0.y *= inv; v0.z *= inv; v0.w *= inv;
    v1.x *= inv; v1.y *= inv; v1.z *= inv; v1.w *= inv;
    p4[tid] = v0;
    p4[tid + 256] = v1;
    ushort4* b4 = (ushort4*)(Pb + row * SS);
    ushort4 u0 = { f2b(v0.x), f2b(v0.y), f2b(v0.z), f2b(v0.w) };
    ushort4 u1 = { f2b(v1.x), f2b(v1.y), f2b(v1.z), f2b(v1.w) };
    b4[tid] = u0;
    b4[tid + 256] = u1;
}

// --------------------------------- x [B,S,H] fp32 -> xT [B,H,S] bf16 (for NT ctx GEMM)
__global__ __launch_bounds__(256) void transpose_cvt(const float* __restrict__ X,
                                                     unsigned short* __restrict__ XT) {
    const int b = blockIdx.z;
    const int t0 = blockIdx.y * 64;
    const int h0 = blockIdx.x * 64;
    __shared__ float tile[64][65];
    const float* Xb = X + (size_t)b * SS * HH;
    unsigned short* Tb = XT + (size_t)b * HH * SS;
#pragma unroll
    for (int q = 0; q < 16; q++) {
        int idx = q * 256 + threadIdx.x;
        int r = idx >> 6, c = idx & 63;
        tile[r][c] = Xb[(size_t)(t0 + r) * HH + h0 + c];
    }
    __syncthreads();
#pragma unroll
    for (int q = 0; q < 16; q++) {
        int idx = q * 256 + threadIdx.x;
        int r = idx >> 6, c = idx & 63;
        Tb[(size_t)(h0 + r) * SS + t0 + c] = f2b(tile[c][r]);
    }
}

// ----------------- ctx = attn @ x (NT bf16 MFMA), 8-phase 256² tile, BK=64, 1-pass
// Same read-hoist restructure as the split-bf16 body (reads post-MFMA in-cluster).
__global__ __launch_bounds__(512, 2) void gemm_ctx_8p(const unsigned short* __restrict__ Ab,
                                                      const unsigned short* __restrict__ Bt,
                                                      float* __restrict__ C) {
    const int b = blockIdx.z;
    const int i0 = blockIdx.y * 256, n0 = blockIdx.x * 256;
    const unsigned short* A = Ab + (size_t)b * SS * SS;
    const unsigned short* B = Bt + (size_t)b * HH * SS;

    __shared__ __align__(16) unsigned short lds[65536];   // 128 KB

    const int tid = threadIdx.x;
    const int wave = tid >> 6, lane = tid & 63;
    const int m16 = lane & 15, quad = lane >> 4;
    const int m7 = m16 & 7;
    const int wy = wave >> 2, wx = wave & 3;
    const int rA8 = tid >> 3;
    const int c8 = (tid & 7) ^ (rA8 & 7);
    const int wt16 = wave * 1024;
    const int sl0 = (quad ^ m7) * 8;          // ushort offset, ks=0 slot
    const int sl1 = ((quad + 4) ^ m7) * 8;    // ks=1 slot

    const size_t aSrc = (size_t)(i0 + rA8) * SS + c8 * 8;
    const size_t bSrc = (size_t)(n0 + ((rA8 >> 5) << 6) + (rA8 & 31)) * SS + c8 * 8;

    f32x4 acc[2][4][2][2] = {};               // [mh][mi][nh][nj]
    bf16x8 a[4][2], bb[2][2][2];              // a[mi][ks], bb[nh][nj][ks]

#define CSTG_A(mh, h, kt, buf) \
    async_load16(A + aSrc + (size_t)((mh) * 64 + (h) * 128) * SS + (size_t)(kt) * 64, \
                 (char*)lds + (buf) * 65536 + (mh) * 16384 + (h) * 8192 + wt16)
#define CSTG_B(nh, h, kt, buf) \
    async_load16(B + bSrc + (size_t)((h) * 128 + (nh) * 32) * SS + (size_t)(kt) * 64, \
                 (char*)lds + (buf) * 65536 + 32768 + (nh) * 16384 + (h) * 8192 + wt16)
#define CRD_A(mh, buf) do { \
        const int r0_ = (buf) * 32768 + ((mh) * 128 + wy * 64 + m16) * 64; \
        _Pragma("unroll") for (int mi = 0; mi < 4; ++mi) { \
            a[mi][0] = *(const bf16x8*)&lds[r0_ + mi * 1024 + sl0]; \
            a[mi][1] = *(const bf16x8*)&lds[r0_ + mi * 1024 + sl1]; \
        } } while (0)
#define CRD_B(nh, buf) do { \
        const int r0_ = (buf) * 32768 + 16384 + (nh) * 8192 + (wx * 32 + m16) * 64; \
        _Pragma("unroll") for (int nj = 0; nj < 2; ++nj) { \
            bb[nh][nj][0] = *(const bf16x8*)&lds[r0_ + nj * 1024 + sl0]; \
            bb[nh][nj][1] = *(const bf16x8*)&lds[r0_ + nj * 1024 + sl1]; \
        } } while (0)
#define CMFMA(mh, nh) \
        __builtin_amdgcn_s_setprio(1); \
        _Pragma("unroll") for (int mi = 0; mi < 4; ++mi) \
        _Pragma("unroll") for (int nj = 0; nj < 2; ++nj) { \
            acc[mh][mi][nh][nj] = __builtin_amdgcn_mfma_f32_16x16x32_bf16(a[mi][0], bb[nh][nj][0], acc[mh][mi][nh][nj], 0, 0, 0); \
            acc[mh][mi][nh][nj] = __builtin_amdgcn_mfma_f32_16x16x32_bf16(a[mi][1], bb[nh][nj][1], acc[mh][mi][nh][nj], 0, 0, 0); \
        } \
        __builtin_amdgcn_s_setprio(0);

    CSTG_A(0, 0, 0, 0); CSTG_A(0, 1, 0, 0);
    CSTG_A(1, 0, 0, 0); CSTG_A(1, 1, 0, 0);
    CSTG_B(0, 0, 0, 0); CSTG_B(0, 1, 0, 0);
    CSTG_B(1, 0, 0, 0); CSTG_B(1, 1, 0, 0);
    CSTG_B(0, 0, 1, 1); CSTG_B(0, 1, 1, 1);
    CSTG_B(1, 0, 1, 1); CSTG_B(1, 1, 1, 1);
    asm volatile("s_waitcnt vmcnt(4)" ::: "memory");
    __builtin_amdgcn_s_barrier();
    CRD_A(0, 0); CRD_B(0, 0); CRD_B(1, 0);

    for (int kt = 0; kt < 32; ++kt) {
        const int bufc = kt & 1, bufn = bufc ^ 1;
        const int ktA = kt < 31 ? kt + 1 : 31;
        const int ktB = kt < 30 ? kt + 2 : 31;
        // ---- ph0 (mh0,nh0)
        CSTG_A(0, 0, ktA, bufn); CSTG_A(0, 1, ktA, bufn);
        __builtin_amdgcn_s_barrier();
        __builtin_amdgcn_sched_barrier(0);
        CMFMA(0, 0)
        __builtin_amdgcn_sched_barrier(0);
        __builtin_amdgcn_s_barrier();
        // ---- ph1 (mh0,nh1)
        asm volatile("s_waitcnt vmcnt(6)" ::: "memory");
        CSTG_A(1, 0, ktA, bufn); CSTG_A(1, 1, ktA, bufn);
        __builtin_amdgcn_s_barrier();
        __builtin_amdgcn_sched_barrier(0);
        CMFMA(0, 1)
        __builtin_amdgcn_sched_barrier(0);
        CRD_A(1, bufc);
        __builtin_amdgcn_s_barrier();
        // ---- ph2 (mh1,nh0)
        asm volatile("s_waitcnt vmcnt(6)" ::: "memory");
        CSTG_B(0, 0, ktB, bufc); CSTG_B(0, 1, ktB, bufc);
        __builtin_amdgcn_s_barrier();
        __builtin_amdgcn_sched_barrier(0);
        CMFMA(1, 0)
        __builtin_amdgcn_sched_barrier(0);
        CRD_B(0, bufn);
        __builtin_amdgcn_s_barrier();
        // ---- ph3 (mh1,nh1)
        asm volatile("s_waitcnt vmcnt(4)" ::: "memory");
        CSTG_B(1, 0, ktB, bufc); CSTG_B(1, 1, ktB, bufc);
        __builtin_amdgcn_s_barrier();
        __builtin_amdgcn_sched_barrier(0);
        CMFMA(1, 1)
        __builtin_amdgcn_sched_barrier(0);
        CRD_B(1, bufn);
        CRD_A(0, bufn);
        __builtin_amdgcn_s_barrier();
    }

    float* Cb = C + (size_t)b * SS * HH;
#pragma unroll
    for (int mh = 0; mh < 2; ++mh)
#pragma unroll
        for (int mi = 0; mi < 4; ++mi)
#pragma unroll
            for (int nh = 0; nh < 2; ++nh)
#pragma unroll
                for (int nj = 0; nj < 2; ++nj) {
                    const int row = i0 + wy * 128 + mh * 64 + mi * 16 + quad * 4;
                    const int col = n0 + wx * 64 + nh * 32 + nj * 16 + m16;
#pragma unroll
                    for (int reg = 0; reg < 4; ++reg)
                        Cb[(size_t)(row + reg) * HH + col] = acc[mh][mi][nh][nj][reg];
                }
#undef CSTG_A
#undef CSTG_B
#undef CRD_A
#undef CRD_B
#undef CMFMA
}

extern "C" void kernel_launch(void* const* d_in, const int* in_sizes, int n_in,
                              void* d_out, int out_size, void* d_ws, size_t ws_size,
                              hipStream_t stream) {
    const float* X = (const float*)d_in[0];   // [8,2048,1024]
    const float* W = (const float*)d_in[1];   // [1024,1024]
    float* ctx  = (float*)d_out;                            // [8,2048,1024]
    float* attn = ctx + (size_t)BB * SS * HH;               // [8,2048,2048]

    char* ws = (char*)d_ws;
    unsigned short* x_hi  = (unsigned short*)ws;                         // [0,32M)
    unsigned short* x_lo  = (unsigned short*)(ws + ((size_t)32 << 20));  // [32,64M)
    unsigned short* wt_hi = (unsigned short*)(ws + ((size_t)64 << 20));  // [64,66M)
    unsigned short* wt_lo = (unsigned short*)(ws + ((size_t)66 << 20));  // [66,68M)
    unsigned short* xT     = x_hi;                                       // after scores
    unsigned short* attn_b = x_lo;                                       // after scores

    unsigned short* xw_hi = (unsigned short*)d_out;   // dead ctx region until final GEMM
    unsigned short* xw_lo = xw_hi + (size_t)BB * SS * HH;

    dim3 blk(256);
    split_x <<<dim3(BB * SS * HH / (8 * 256)), blk, 0, stream>>>(X, x_hi, x_lo);
    split_wT<<<dim3(HH / 64, HH / 64), blk, 0, stream>>>(W, wt_hi, wt_lo);
    gemm_xw3_8p<<<dim3(HH / 256, SS / 256, BB), dim3(512), 0, stream>>>(x_hi, x_lo, wt_hi, wt_lo, xw_hi, xw_lo);
    gemm_sc3_8p<<<dim3(SS / 256, SS / 256, BB), dim3(512), 0, stream>>>(xw_hi, xw_lo, x_hi, x_lo, attn);
    transpose_cvt<<<dim3(HH / 64, SS / 64, BB), blk, 0, stream>>>(X, xT);
    softmax_rows <<<dim3(BB * SS), blk, 0, stream>>>(attn, attn_b);
    gemm_ctx_8p<<<dim3(HH / 256, SS / 256, BB), dim3(512), 0, stream>>>(attn_b, xT, ctx);
}